// Round 11
// baseline (299.138 us; speedup 1.0000x reference)
//
#include <hip/hip_runtime.h>
#include <hip/hip_bf16.h>

typedef __bf16 bf16;
typedef __bf16 bf16x8 __attribute__((ext_vector_type(8)));
typedef float f32x4 __attribute__((ext_vector_type(4)));
typedef unsigned short u16;

// workspace offsets (bytes)
static constexpr size_t OFF_Q    = 0;          // [16][8][1024][32] bf16  (q pre-scaled by 32^-0.5)
static constexpr size_t OFF_K    = 8388608;    // [16][8][1024][32] bf16
static constexpr size_t OFF_VT   = 16777216;   // [16][8][32][1024] bf16 (V transposed)
static constexpr size_t OFF_Y    = 25165824;   // [16][1024][256]  bf16 (attn out) -- xb aliases this
static constexpr size_t OFF_COMB = 33554432;   // [2][8][64][64]   f32
static constexpr size_t OFF_PWB  = 33816576;   // [256][256]  bf16 proj weight
static constexpr size_t OFF_WB   = 33947648;   // [768][256]  bf16 qkv weight
static constexpr size_t OFF_BMAX = 34340864;   // [16] f32 per-(b,h) bias max
static constexpr size_t OFF_GM   = 34340928;   // [128] f32 per-(wid,h) softmax shift M

__device__ __forceinline__ int clampi(int v, int lo, int hi) {
  return v < lo ? lo : (v > hi ? hi : v);
}

__device__ __forceinline__ void glds16(const bf16* src, bf16* dst) {
  __builtin_amdgcn_global_load_lds((const __attribute__((address_space(1))) void*)src,
                                   (__attribute__((address_space(3))) void*)dst,
                                   16, 0, 0);
}

__device__ __forceinline__ bf16x8 cvt8(const float* p) {
  f32x4 a = *(const f32x4*)p;
  f32x4 b = *(const f32x4*)(p + 4);
  bf16x8 r;
  r[0] = (bf16)a[0]; r[1] = (bf16)a[1]; r[2] = (bf16)a[2]; r[3] = (bf16)a[3];
  r[4] = (bf16)b[0]; r[5] = (bf16)b[1]; r[6] = (bf16)b[2]; r[7] = (bf16)b[3];
  return r;
}

// ---------------- kernel 1: combined bias table + per-(b,h) bias max ----------------
__global__ void build_comb_k(const float* __restrict__ loc, const float* __restrict__ tt,
                             const float* __restrict__ tx, const float* __restrict__ ty,
                             const float* __restrict__ tz, float* __restrict__ comb,
                             float* __restrict__ bmax) {
  const int b = blockIdx.x >> 3, h = blockIdx.x & 7;
  __shared__ float st[256];
  __shared__ float red[256];
  const int t = threadIdx.x;
  {
    const int i = t >> 4, j = t & 15;
    const float* li = loc + (b * 16 + i) * 3;
    const float* lj = loc + (b * 16 + j) * 3;
    const float G = (float)(111.32 / 100.0);
    float dx = li[0] - lj[0];
    float dy = li[1] - lj[1];
    float dz = li[2] - lj[2];
    int ix = clampi((int)rintf(dx / G + 25.0f), 0, 50);
    int iy = clampi((int)rintf(dy / G + 25.0f), 0, 50);
    int iz = clampi((int)rintf(dz / G + 5.0f), 0, 10);
    st[t] = tx[ix * 8 + h] + ty[iy * 8 + h] + tz[iz * 8 + h];
  }
  __syncthreads();
  float* out = comb + blockIdx.x * 4096;
  float lm = -1e30f;
  for (int e = t; e < 4096; e += 256) {
    int a = e >> 6, c = e & 63;
    float v = tt[(a - c + 63) * 8 + h] + st[((a & 15) << 4) | (c & 15)];
    out[e] = v;
    lm = fmaxf(lm, v);
  }
  red[t] = lm;
  __syncthreads();
  for (int s = 128; s > 0; s >>= 1) {
    if (t < s) red[t] = fmaxf(red[t], red[t + s]);
    __syncthreads();
  }
  if (t == 0) bmax[blockIdx.x] = red[0];
}

// ---------------- kernel 1b: x fp32 -> xb bf16 [16384][256], roll+window gather fused ----
__global__ __launch_bounds__(256) void cvt_x_k(const float* __restrict__ x, bf16* __restrict__ xb) {
  const int tid = blockIdx.x * 256 + threadIdx.x;
  const int e = tid * 8;
  const int m = e >> 8, k = e & 255;
  const int wid = m >> 10, n = m & 1023;
  const int bb = wid >> 3, wi = wid & 7, tw = n >> 4, ww = n & 15;
  const int hh = (wi * 64 + tw + 32) & 511;          // roll(x, -32)
  const float* src = x + (((bb * 512 + hh) * 16 + ww) << 8) + k;
  *(bf16x8*)(xb + e) = cvt8(src);
}

// ---------------- kernel 1c: qkv weight + proj weight fp32 -> bf16 ----------------
__global__ __launch_bounds__(256) void cvt_w_k(const float* __restrict__ w, const float* __restrict__ pw,
                                               bf16* __restrict__ wb, bf16* __restrict__ pwb) {
  const int tid = blockIdx.x * 256 + threadIdx.x;
  const int e = tid * 8;
  if (e < 768 * 256) {
    *(bf16x8*)(wb + e) = cvt8(w + e);
  } else {
    const int e2 = e - 768 * 256;
    *(bf16x8*)(pwb + e2) = cvt8(pw + e2);
  }
}

// ---------------- kernel 2: QKV GEMM, LDS-staged, swizzled; q pre-scaled ----------------
__global__ __launch_bounds__(256) void qkv_k(const bf16* __restrict__ xb, const bf16* __restrict__ wb,
                                             const float* __restrict__ qb, bf16* __restrict__ qws,
                                             bf16* __restrict__ kws, bf16* __restrict__ vtws) {
  __shared__ __align__(16) bf16 lA[128 * 64];
  __shared__ __align__(16) bf16 lB[128 * 64];
  const int lane = threadIdx.x & 63, wv = threadIdx.x >> 6;
  const int rr = lane & 15, g = lane >> 4;
  const int wr = wv >> 1, wc = wv & 1;
  const int bid = blockIdx.x;
  const int tt = (bid & 7) * 96 + (bid >> 3);
  const int mtile = tt / 6, ntile = tt % 6;
  const int mb = mtile * 128, nb2 = ntile * 128;
  const int arow = lane >> 3;
  const int sg = ((lane & 7) ^ arow) << 3;
  const int axor = rr & 7;
  f32x4 acc[4][4] = {};
  for (int kb = 0; kb < 256; kb += 64) {
#pragma unroll
    for (int q = 0; q < 4; ++q) {
      const int rowp = (wv * 4 + q) * 8 + arow;
      glds16(xb + (mb + rowp) * 256 + kb + sg, &lA[(wv * 4 + q) * 512]);
      glds16(wb + (nb2 + rowp) * 256 + kb + sg, &lB[(wv * 4 + q) * 512]);
    }
    __syncthreads();
#pragma unroll
    for (int ks = 0; ks < 2; ++ks) {
      bf16x8 af[4], bfr[4];
#pragma unroll
      for (int rt = 0; rt < 4; ++rt)
        af[rt] = *(const bf16x8*)&lA[(wr * 64 + rt * 16 + rr) * 64 + (((ks << 2) | g) ^ axor) * 8];
#pragma unroll
      for (int ct = 0; ct < 4; ++ct)
        bfr[ct] = *(const bf16x8*)&lB[(wc * 64 + ct * 16 + rr) * 64 + (((ks << 2) | g) ^ axor) * 8];
#pragma unroll
      for (int rt = 0; rt < 4; ++rt)
#pragma unroll
        for (int ct = 0; ct < 4; ++ct)
          acc[rt][ct] = __builtin_amdgcn_mfma_f32_16x16x32_bf16(af[rt], bfr[ct], acc[rt][ct], 0, 0, 0);
    }
    __syncthreads();
  }
  const int qkvi = (nb2 >> 8);
  const float mult = (qkvi == 0) ? 0.17677669529663687f : 1.0f;  // fold 32^-0.5 into q
#pragma unroll
  for (int ct = 0; ct < 4; ++ct) {
    const int c2 = nb2 + wc * 64 + ct * 16 + rr;
    const float bc = qb[c2];
    const int h2 = (c2 & 255) >> 5, d = c2 & 31;
#pragma unroll
    for (int rt = 0; rt < 4; ++rt) {
      const int m0 = mb + wr * 64 + rt * 16 + g * 4;
      const int wid = m0 >> 10, n0 = m0 & 1023;
      if (qkvi == 2) {
        union { u16 us[4]; uint2 u2; } pk;
#pragma unroll
        for (int r = 0; r < 4; ++r) {
          bf16 bv = (bf16)(acc[rt][ct][r] + bc);
          pk.us[r] = *(const u16*)&bv;
        }
        *(uint2*)(vtws + ((size_t)((wid * 8 + h2) * 32 + d) << 10) + n0) = pk.u2;
      } else {
        bf16* bp = (qkvi ? kws : qws) + ((size_t)(wid * 8 + h2) << 15) + d;
#pragma unroll
        for (int r = 0; r < 4; ++r) bp[(size_t)(n0 + r) << 5] = (bf16)((acc[rt][ct][r] + bc) * mult);
      }
    }
  }
}

// ---------------- kernel 2b: per-group softmax shift M = max||q'||*max||k|| + bmax ----
__global__ __launch_bounds__(256) void norm_k(const bf16* __restrict__ qws, const bf16* __restrict__ kws,
                                              const float* __restrict__ bmax, float* __restrict__ gM) {
  const int grp = blockIdx.x;                 // wid*8 + h
  const int t = threadIdx.x;
  const bf16* qb = qws + ((size_t)grp << 15);
  const bf16* kb = kws + ((size_t)grp << 15);
  float qm = 0.0f, km = 0.0f;
#pragma unroll
  for (int rw = 0; rw < 4; ++rw) {
    const int r = rw * 256 + t;
    float sq = 0.0f, sk = 0.0f;
#pragma unroll
    for (int d8 = 0; d8 < 4; ++d8) {
      bf16x8 vq = *(const bf16x8*)(qb + r * 32 + d8 * 8);
      bf16x8 vk = *(const bf16x8*)(kb + r * 32 + d8 * 8);
#pragma unroll
      for (int e = 0; e < 8; ++e) {
        float a = (float)vq[e]; sq += a * a;
        float c = (float)vk[e]; sk += c * c;
      }
    }
    qm = fmaxf(qm, sq); km = fmaxf(km, sk);
  }
  __shared__ float rq[256], rk[256];
  rq[t] = qm; rk[t] = km;
  __syncthreads();
  for (int s = 128; s > 0; s >>= 1) {
    if (t < s) { rq[t] = fmaxf(rq[t], rq[t + s]); rk[t] = fmaxf(rk[t], rk[t + s]); }
    __syncthreads();
  }
  if (t == 0) {
    const int b = grp >> 6, h = grp & 7;
    gM[grp] = sqrtf(rq[0] * rk[0]) * 1.0005f + bmax[b * 8 + h] + 0.01f;
  }
}

// ---------------- kernel 3: attention v9 — dual-q, 32-key chunks, explicit 1-chunk prefetch ----
// r10 structure (spill-free at VGPR 56) + r8's cur/nxt rotation at half the buffer count:
// per chunk only 4 loads (16 VGPR nxt set), so peak pressure ~120 < 128 (launch_bounds 256,4).
__global__ __launch_bounds__(256, 4)
void attn_k(const bf16* __restrict__ qws, const bf16* __restrict__ kws,
            const bf16* __restrict__ vtws, const float* __restrict__ comb,
            const float* __restrict__ gM, bf16* __restrict__ yws) {
  const int lane = threadIdx.x & 63, wv = threadIdx.x >> 6;
  const int rr = lane & 15, g = lane >> 4;
  const int id = blockIdx.x;
  const int xcd = id & 7, t2 = id >> 3;
  const int qt = t2 & 7, gh = t2 >> 3;
  const int grp = gh * 8 + xcd;                 // bijective; 8 qt-blocks per grp on same XCD
  const int h = grp & 7, wid = grp >> 3;
  const int b = wid >> 3;
  const bool win7 = (wid & 7) == 7;
  const int iA = qt * 128 + wv * 16 + rr;       // q-rows (thread-local); iB = iA + 64
  const int iB = iA + 64;
  const bf16* qbase = qws + ((size_t)grp << 15);
  const bf16* kbase = kws + ((size_t)grp << 15);
  const bf16* vbase = vtws + ((size_t)grp << 15);
  const bf16x8 qfA = *(const bf16x8*)(qbase + (iA << 5) + g * 8);  // pre-scaled q
  const bf16x8 qfB = *(const bf16x8*)(qbase + (iB << 5) + g * 8);
  // (iA+64)&63 == iA&63  -> comb row shared; 512%128==0 -> mask side shared.
  const float* crow = comb + (b * 8 + h) * 4096 + (iA & 63) * 64;
  f32x4 b00 = *(const f32x4*)(crow + g * 8);        // keys kb(64-align) + 8g + r
  f32x4 b01 = *(const f32x4*)(crow + g * 8 + 4);    // keys kb + 8g + 4 + r
  f32x4 b10 = *(const f32x4*)(crow + 32 + g * 8);   // keys kb+32 + 8g + r
  f32x4 b11 = *(const f32x4*)(crow + 32 + g * 8 + 4);
  const bool ilow = iA < 512;
  const float M = gM[grp];
  const float cLo = ((win7 && !ilow) ? -100.0f : 0.0f) - M;
  const float cHi = ((win7 && ilow) ? -100.0f : 0.0f) - M;
#pragma unroll
  for (int r = 0; r < 4; ++r) { b00[r] += cLo; b01[r] += cLo; b10[r] += cLo; b11[r] += cLo; }

  const int kp = 8 * (rr >> 2) + (rr & 3);      // permuted K-row so P^T feeds PV B-frag
  const bf16* krow = kbase + (kp << 5) + g * 8; // row stride 32 elems
  const bf16* vrow0 = vbase + (rr << 10) + g * 8;
  const bf16* vrow1 = vbase + ((16 + rr) << 10) + g * 8;

  f32x4 o0A = {}, o1A = {}, o0B = {}, o1B = {};
  f32x4 laA = {}, laB = {};

  // prologue: chunk 0 into cur regs
  bf16x8 cKA = *(const bf16x8*)(krow);
  bf16x8 cKB = *(const bf16x8*)(krow + (4 << 5));
  bf16x8 cVA = *(const bf16x8*)(vrow0);
  bf16x8 cVB = *(const bf16x8*)(vrow1);

  // one 32-key chunk C (keys C*32..C*32+31): prefetch chunk C+1, compute on cur, rotate.
#define ATTN_STEP32P(C, B0, B1)                                                        \
  {                                                                                    \
    bf16x8 nKA, nKB, nVA, nVB;                                                         \
    if ((C) < 31) {                                                                    \
      const int kn_ = ((C) + 1) * 32;                                                  \
      nKA = *(const bf16x8*)(krow + (kn_ << 5));                                       \
      nKB = *(const bf16x8*)(krow + ((kn_ + 4) << 5));                                 \
      nVA = *(const bf16x8*)(vrow0 + kn_);                                             \
      nVB = *(const bf16x8*)(vrow1 + kn_);                                             \
    } else {                                                                           \
      nKA = cKA; nKB = cKB; nVA = cVA; nVB = cVB;                                      \
    }                                                                                  \
    f32x4 zero = {};                                                                   \
    f32x4 sA0 = __builtin_amdgcn_mfma_f32_16x16x32_bf16(cKA, qfA, zero, 0, 0, 0);      \
    f32x4 sA1 = __builtin_amdgcn_mfma_f32_16x16x32_bf16(cKB, qfA, zero, 0, 0, 0);      \
    f32x4 sB0 = __builtin_amdgcn_mfma_f32_16x16x32_bf16(cKA, qfB, zero, 0, 0, 0);      \
    f32x4 sB1 = __builtin_amdgcn_mfma_f32_16x16x32_bf16(cKB, qfB, zero, 0, 0, 0);      \
    f32x4 pA0, pA1, pB0, pB1;                                                          \
    _Pragma("unroll")                                                                  \
    for (int r = 0; r < 4; ++r) {                                                      \
      pA0[r] = __expf(sA0[r] + B0[r]); pA1[r] = __expf(sA1[r] + B1[r]);                \
      pB0[r] = __expf(sB0[r] + B0[r]); pB1[r] = __expf(sB1[r] + B1[r]);                \
    }                                                                                  \
    laA += pA0 + pA1; laB += pB0 + pB1;                                                \
    bf16x8 paA, paB;                                                                   \
    _Pragma("unroll")                                                                  \
    for (int r = 0; r < 4; ++r) {                                                      \
      paA[r] = (bf16)pA0[r]; paA[r + 4] = (bf16)pA1[r];                                \
      paB[r] = (bf16)pB0[r]; paB[r + 4] = (bf16)pB1[r];                                \
    }                                                                                  \
    o0A = __builtin_amdgcn_mfma_f32_16x16x32_bf16(cVA, paA, o0A, 0, 0, 0);             \
    o1A = __builtin_amdgcn_mfma_f32_16x16x32_bf16(cVB, paA, o1A, 0, 0, 0);             \
    o0B = __builtin_amdgcn_mfma_f32_16x16x32_bf16(cVA, paB, o0B, 0, 0, 0);             \
    o1B = __builtin_amdgcn_mfma_f32_16x16x32_bf16(cVB, paB, o1B, 0, 0, 0);             \
    cKA = nKA; cKB = nKB; cVA = nVA; cVB = nVB;                                        \
  }

#pragma unroll
  for (int t = 0; t < 8; ++t) {
    ATTN_STEP32P(2 * t, b00, b01);
    ATTN_STEP32P(2 * t + 1, b10, b11);
  }
  {
    const float dlt = cHi - cLo;
#pragma unroll
    for (int r = 0; r < 4; ++r) { b00[r] += dlt; b01[r] += dlt; b10[r] += dlt; b11[r] += dlt; }
  }
#pragma unroll
  for (int t = 8; t < 16; ++t) {
    ATTN_STEP32P(2 * t, b00, b01);
    ATTN_STEP32P(2 * t + 1, b10, b11);
  }
#undef ATTN_STEP32P

  // epilogue: per-fragment row-sum reduction (2 shuffles each) + store
  {
    float l = (laA[0] + laA[1]) + (laA[2] + laA[3]);
    l += __shfl_xor(l, 16);
    l += __shfl_xor(l, 32);
    const float inv = 1.0f / l;
    bf16* ybase = yws + (size_t)((wid << 10) + iA) * 256 + h * 32;
    union { u16 us[4]; uint2 u2; } pk;
#pragma unroll
    for (int r = 0; r < 4; ++r) { bf16 bv = (bf16)(o0A[r] * inv); pk.us[r] = *(const u16*)&bv; }
    *(uint2*)(ybase + g * 4) = pk.u2;
#pragma unroll
    for (int r = 0; r < 4; ++r) { bf16 bv = (bf16)(o1A[r] * inv); pk.us[r] = *(const u16*)&bv; }
    *(uint2*)(ybase + 16 + g * 4) = pk.u2;
  }
  {
    float l = (laB[0] + laB[1]) + (laB[2] + laB[3]);
    l += __shfl_xor(l, 16);
    l += __shfl_xor(l, 32);
    const float inv = 1.0f / l;
    bf16* ybase = yws + (size_t)((wid << 10) + iB) * 256 + h * 32;
    union { u16 us[4]; uint2 u2; } pk;
#pragma unroll
    for (int r = 0; r < 4; ++r) { bf16 bv = (bf16)(o0B[r] * inv); pk.us[r] = *(const u16*)&bv; }
    *(uint2*)(ybase + g * 4) = pk.u2;
#pragma unroll
    for (int r = 0; r < 4; ++r) { bf16 bv = (bf16)(o1B[r] * inv); pk.us[r] = *(const u16*)&bv; }
    *(uint2*)(ybase + 16 + g * 4) = pk.u2;
  }
}

// ---------------- kernel 4: proj GEMM, roll-back scatter ----------------
__global__ __launch_bounds__(256) void proj_k(const bf16* __restrict__ yws, const bf16* __restrict__ pwb,
                                              const float* __restrict__ pb, float* __restrict__ out) {
  __shared__ __align__(16) bf16 lA[128 * 64];
  __shared__ __align__(16) bf16 lB[128 * 64];
  const int lane = threadIdx.x & 63, wv = threadIdx.x >> 6;
  const int rr = lane & 15, g = lane >> 4;
  const int wr = wv >> 1, wc = wv & 1;
  const int bid = blockIdx.x;
  const int tt = (bid & 7) * 32 + (bid >> 3);
  const int mtile = tt >> 1, ntile = tt & 1;
  const int mb = mtile * 128, nb2 = ntile * 128;
  const int arow = lane >> 3;
  const int sg = ((lane & 7) ^ arow) << 3;
  const int axor = rr & 7;
  f32x4 acc[4][4] = {};
  for (int kb = 0; kb < 256; kb += 64) {
#pragma unroll
    for (int q = 0; q < 4; ++q) {
      const int rowp = (wv * 4 + q) * 8 + arow;
      glds16(yws + (size_t)(mb + rowp) * 256 + kb + sg, &lA[(wv * 4 + q) * 512]);
      glds16(pwb + (nb2 + rowp) * 256 + kb + sg, &lB[(wv * 4 + q) * 512]);
    }
    __syncthreads();
#pragma unroll
    for (int ks = 0; ks < 2; ++ks) {
      bf16x8 af[4], bfr[4];
#pragma unroll
      for (int rt = 0; rt < 4; ++rt)
        af[rt] = *(const bf16x8*)&lA[(wr * 64 + rt * 16 + rr) * 64 + (((ks << 2) | g) ^ axor) * 8];
#pragma unroll
      for (int ct = 0; ct < 4; ++ct)
        bfr[ct] = *(const bf16x8*)&lB[(wc * 64 + ct * 16 + rr) * 64 + (((ks << 2) | g) ^ axor) * 8];
#pragma unroll
      for (int rt = 0; rt < 4; ++rt)
#pragma unroll
        for (int ct = 0; ct < 4; ++ct)
          acc[rt][ct] = __builtin_amdgcn_mfma_f32_16x16x32_bf16(af[rt], bfr[ct], acc[rt][ct], 0, 0, 0);
    }
    __syncthreads();
  }
#pragma unroll
  for (int ct = 0; ct < 4; ++ct) {
    const int c2 = nb2 + wc * 64 + ct * 16 + rr;
    const float bc = pb[c2];
#pragma unroll
    for (int rt = 0; rt < 4; ++rt) {
#pragma unroll
      for (int r = 0; r < 4; ++r) {
        const int m = mb + wr * 64 + rt * 16 + g * 4 + r;
        const int wid = m >> 10, n = m & 1023;
        const int bb = wid >> 3;
        const int hh = ((wid & 7) * 64 + (n >> 4) + 32) & 511;  // roll(out, +32)
        out[(((bb * 512 + hh) * 16 + (n & 15)) << 8) + c2] = acc[rt][ct][r] + bc;
      }
    }
  }
}

extern "C" void kernel_launch(void* const* d_in, const int* in_sizes, int n_in,
                              void* d_out, int out_size, void* d_ws, size_t ws_size,
                              hipStream_t stream) {
  const float* x     = (const float*)d_in[0];
  const float* loc   = (const float*)d_in[1];
  const float* qkvw  = (const float*)d_in[2];
  const float* qkvb  = (const float*)d_in[3];
  const float* projw = (const float*)d_in[4];
  const float* projb = (const float*)d_in[5];
  const float* tt    = (const float*)d_in[6];
  const float* tx    = (const float*)d_in[7];
  const float* ty    = (const float*)d_in[8];
  const float* tz    = (const float*)d_in[9];
  char* ws = (char*)d_ws;
  bf16* qws   = (bf16*)(ws + OFF_Q);
  bf16* kws   = (bf16*)(ws + OFF_K);
  bf16* vtws  = (bf16*)(ws + OFF_VT);
  bf16* yws   = (bf16*)(ws + OFF_Y);
  bf16* xb    = (bf16*)(ws + OFF_Y);     // aliases yws; dead before attn writes
  float* comb = (float*)(ws + OFF_COMB);
  bf16* pwb   = (bf16*)(ws + OFF_PWB);
  bf16* wb    = (bf16*)(ws + OFF_WB);
  float* bmax = (float*)(ws + OFF_BMAX);
  float* gM   = (float*)(ws + OFF_GM);
  float* out = (float*)d_out;

  build_comb_k<<<16, 256, 0, stream>>>(loc, tt, tx, ty, tz, comb, bmax);
  cvt_x_k<<<2048, 256, 0, stream>>>(x, xb);
  cvt_w_k<<<128, 256, 0, stream>>>(qkvw, projw, wb, pwb);
  qkv_k<<<768, 256, 0, stream>>>(xb, wb, qkvb, qws, kws, vtws);
  norm_k<<<128, 256, 0, stream>>>(qws, kws, bmax, gM);
  attn_k<<<1024, 256, 0, stream>>>(qws, kws, vtws, comb, gM, yws);
  proj_k<<<256, 256, 0, stream>>>(yws, pwb, projb, out);
}

// Round 12
// 298.642 us; speedup vs baseline: 1.0017x; 1.0017x over previous
//
#include <hip/hip_runtime.h>
#include <hip/hip_bf16.h>

typedef __bf16 bf16;
typedef __bf16 bf16x8 __attribute__((ext_vector_type(8)));
typedef float f32x4 __attribute__((ext_vector_type(4)));
typedef unsigned short u16;

// workspace offsets (bytes)
static constexpr size_t OFF_Q    = 0;          // [16][8][1024][32] bf16  (q pre-scaled by 32^-0.5)
static constexpr size_t OFF_K    = 8388608;    // [16][8][1024][32] bf16
static constexpr size_t OFF_VT   = 16777216;   // [16][8][32][1024] bf16 (V transposed)
static constexpr size_t OFF_Y    = 25165824;   // [16][1024][256]  bf16 (attn out) -- xb aliases this
static constexpr size_t OFF_COMB = 33554432;   // [2][8][64][64]   f32
static constexpr size_t OFF_PWB  = 33816576;   // [256][256]  bf16 proj weight
static constexpr size_t OFF_WB   = 33947648;   // [768][256]  bf16 qkv weight
static constexpr size_t OFF_BMAX = 34340864;   // [16] f32 per-(b,h) bias max
static constexpr size_t OFF_GM   = 34340928;   // [128] f32 per-(wid,h) softmax shift M

__device__ __forceinline__ int clampi(int v, int lo, int hi) {
  return v < lo ? lo : (v > hi ? hi : v);
}

__device__ __forceinline__ void glds16(const bf16* src, bf16* dst) {
  __builtin_amdgcn_global_load_lds((const __attribute__((address_space(1))) void*)src,
                                   (__attribute__((address_space(3))) void*)dst,
                                   16, 0, 0);
}

__device__ __forceinline__ bf16x8 cvt8(const float* p) {
  f32x4 a = *(const f32x4*)p;
  f32x4 b = *(const f32x4*)(p + 4);
  bf16x8 r;
  r[0] = (bf16)a[0]; r[1] = (bf16)a[1]; r[2] = (bf16)a[2]; r[3] = (bf16)a[3];
  r[4] = (bf16)b[0]; r[5] = (bf16)b[1]; r[6] = (bf16)b[2]; r[7] = (bf16)b[3];
  return r;
}

// ---------------- kernel 1: combined bias table + per-(b,h) bias max ----------------
__global__ void build_comb_k(const float* __restrict__ loc, const float* __restrict__ tt,
                             const float* __restrict__ tx, const float* __restrict__ ty,
                             const float* __restrict__ tz, float* __restrict__ comb,
                             float* __restrict__ bmax) {
  const int b = blockIdx.x >> 3, h = blockIdx.x & 7;
  __shared__ float st[256];
  __shared__ float red[256];
  const int t = threadIdx.x;
  {
    const int i = t >> 4, j = t & 15;
    const float* li = loc + (b * 16 + i) * 3;
    const float* lj = loc + (b * 16 + j) * 3;
    const float G = (float)(111.32 / 100.0);
    float dx = li[0] - lj[0];
    float dy = li[1] - lj[1];
    float dz = li[2] - lj[2];
    int ix = clampi((int)rintf(dx / G + 25.0f), 0, 50);
    int iy = clampi((int)rintf(dy / G + 25.0f), 0, 50);
    int iz = clampi((int)rintf(dz / G + 5.0f), 0, 10);
    st[t] = tx[ix * 8 + h] + ty[iy * 8 + h] + tz[iz * 8 + h];
  }
  __syncthreads();
  float* out = comb + blockIdx.x * 4096;
  float lm = -1e30f;
  for (int e = t; e < 4096; e += 256) {
    int a = e >> 6, c = e & 63;
    float v = tt[(a - c + 63) * 8 + h] + st[((a & 15) << 4) | (c & 15)];
    out[e] = v;
    lm = fmaxf(lm, v);
  }
  red[t] = lm;
  __syncthreads();
  for (int s = 128; s > 0; s >>= 1) {
    if (t < s) red[t] = fmaxf(red[t], red[t + s]);
    __syncthreads();
  }
  if (t == 0) bmax[blockIdx.x] = red[0];
}

// ---------------- kernel 1b: x fp32 -> xb bf16 [16384][256], roll+window gather fused ----
__global__ __launch_bounds__(256) void cvt_x_k(const float* __restrict__ x, bf16* __restrict__ xb) {
  const int tid = blockIdx.x * 256 + threadIdx.x;
  const int e = tid * 8;
  const int m = e >> 8, k = e & 255;
  const int wid = m >> 10, n = m & 1023;
  const int bb = wid >> 3, wi = wid & 7, tw = n >> 4, ww = n & 15;
  const int hh = (wi * 64 + tw + 32) & 511;          // roll(x, -32)
  const float* src = x + (((bb * 512 + hh) * 16 + ww) << 8) + k;
  *(bf16x8*)(xb + e) = cvt8(src);
}

// ---------------- kernel 1c: qkv weight + proj weight fp32 -> bf16 ----------------
__global__ __launch_bounds__(256) void cvt_w_k(const float* __restrict__ w, const float* __restrict__ pw,
                                               bf16* __restrict__ wb, bf16* __restrict__ pwb) {
  const int tid = blockIdx.x * 256 + threadIdx.x;
  const int e = tid * 8;
  if (e < 768 * 256) {
    *(bf16x8*)(wb + e) = cvt8(w + e);
  } else {
    const int e2 = e - 768 * 256;
    *(bf16x8*)(pwb + e2) = cvt8(pw + e2);
  }
}

// ---------------- kernel 2: QKV GEMM, LDS-staged, swizzled; q pre-scaled ----------------
__global__ __launch_bounds__(256) void qkv_k(const bf16* __restrict__ xb, const bf16* __restrict__ wb,
                                             const float* __restrict__ qb, bf16* __restrict__ qws,
                                             bf16* __restrict__ kws, bf16* __restrict__ vtws) {
  __shared__ __align__(16) bf16 lA[128 * 64];
  __shared__ __align__(16) bf16 lB[128 * 64];
  const int lane = threadIdx.x & 63, wv = threadIdx.x >> 6;
  const int rr = lane & 15, g = lane >> 4;
  const int wr = wv >> 1, wc = wv & 1;
  const int bid = blockIdx.x;
  const int tt = (bid & 7) * 96 + (bid >> 3);
  const int mtile = tt / 6, ntile = tt % 6;
  const int mb = mtile * 128, nb2 = ntile * 128;
  const int arow = lane >> 3;
  const int sg = ((lane & 7) ^ arow) << 3;
  const int axor = rr & 7;
  f32x4 acc[4][4] = {};
  for (int kb = 0; kb < 256; kb += 64) {
#pragma unroll
    for (int q = 0; q < 4; ++q) {
      const int rowp = (wv * 4 + q) * 8 + arow;
      glds16(xb + (mb + rowp) * 256 + kb + sg, &lA[(wv * 4 + q) * 512]);
      glds16(wb + (nb2 + rowp) * 256 + kb + sg, &lB[(wv * 4 + q) * 512]);
    }
    __syncthreads();
#pragma unroll
    for (int ks = 0; ks < 2; ++ks) {
      bf16x8 af[4], bfr[4];
#pragma unroll
      for (int rt = 0; rt < 4; ++rt)
        af[rt] = *(const bf16x8*)&lA[(wr * 64 + rt * 16 + rr) * 64 + (((ks << 2) | g) ^ axor) * 8];
#pragma unroll
      for (int ct = 0; ct < 4; ++ct)
        bfr[ct] = *(const bf16x8*)&lB[(wc * 64 + ct * 16 + rr) * 64 + (((ks << 2) | g) ^ axor) * 8];
#pragma unroll
      for (int rt = 0; rt < 4; ++rt)
#pragma unroll
        for (int ct = 0; ct < 4; ++ct)
          acc[rt][ct] = __builtin_amdgcn_mfma_f32_16x16x32_bf16(af[rt], bfr[ct], acc[rt][ct], 0, 0, 0);
    }
    __syncthreads();
  }
  const int qkvi = (nb2 >> 8);
  const float mult = (qkvi == 0) ? 0.17677669529663687f : 1.0f;  // fold 32^-0.5 into q
#pragma unroll
  for (int ct = 0; ct < 4; ++ct) {
    const int c2 = nb2 + wc * 64 + ct * 16 + rr;
    const float bc = qb[c2];
    const int h2 = (c2 & 255) >> 5, d = c2 & 31;
#pragma unroll
    for (int rt = 0; rt < 4; ++rt) {
      const int m0 = mb + wr * 64 + rt * 16 + g * 4;
      const int wid = m0 >> 10, n0 = m0 & 1023;
      if (qkvi == 2) {
        union { u16 us[4]; uint2 u2; } pk;
#pragma unroll
        for (int r = 0; r < 4; ++r) {
          bf16 bv = (bf16)(acc[rt][ct][r] + bc);
          pk.us[r] = *(const u16*)&bv;
        }
        *(uint2*)(vtws + ((size_t)((wid * 8 + h2) * 32 + d) << 10) + n0) = pk.u2;
      } else {
        bf16* bp = (qkvi ? kws : qws) + ((size_t)(wid * 8 + h2) << 15) + d;
#pragma unroll
        for (int r = 0; r < 4; ++r) bp[(size_t)(n0 + r) << 5] = (bf16)((acc[rt][ct][r] + bc) * mult);
      }
    }
  }
}

// ---------------- kernel 2b: per-group softmax shift M = max||q'||*max||k|| + bmax ----
__global__ __launch_bounds__(256) void norm_k(const bf16* __restrict__ qws, const bf16* __restrict__ kws,
                                              const float* __restrict__ bmax, float* __restrict__ gM) {
  const int grp = blockIdx.x;                 // wid*8 + h
  const int t = threadIdx.x;
  const bf16* qb = qws + ((size_t)grp << 15);
  const bf16* kb = kws + ((size_t)grp << 15);
  float qm = 0.0f, km = 0.0f;
#pragma unroll
  for (int rw = 0; rw < 4; ++rw) {
    const int r = rw * 256 + t;
    float sq = 0.0f, sk = 0.0f;
#pragma unroll
    for (int d8 = 0; d8 < 4; ++d8) {
      bf16x8 vq = *(const bf16x8*)(qb + r * 32 + d8 * 8);
      bf16x8 vk = *(const bf16x8*)(kb + r * 32 + d8 * 8);
#pragma unroll
      for (int e = 0; e < 8; ++e) {
        float a = (float)vq[e]; sq += a * a;
        float c = (float)vk[e]; sk += c * c;
      }
    }
    qm = fmaxf(qm, sq); km = fmaxf(km, sk);
  }
  __shared__ float rq[256], rk[256];
  rq[t] = qm; rk[t] = km;
  __syncthreads();
  for (int s = 128; s > 0; s >>= 1) {
    if (t < s) { rq[t] = fmaxf(rq[t], rq[t + s]); rk[t] = fmaxf(rk[t], rk[t + s]); }
    __syncthreads();
  }
  if (t == 0) {
    const int b = grp >> 6, h = grp & 7;
    gM[grp] = sqrtf(rq[0] * rk[0]) * 1.0005f + bmax[b * 8 + h] + 0.01f;
  }
}

// ---------------- kernel 3: attention v10 — dual-q, 32-key chunks, IN-PLACE rotated loads ----
// Exactly r10's register footprint (VGPR 56, no spill). Pipelining comes from load
// PLACEMENT only: cK* are overwritten with chunk t+1 right after the QK MFMAs issue
// (WAR resolves at issue), cV* right after the PV MFMAs — each load's s_waitcnt then
// has ~300+ cycles of independent VALU/MFMA in front of it. Zero extra registers.
__global__ __launch_bounds__(256, 4)
void attn_k(const bf16* __restrict__ qws, const bf16* __restrict__ kws,
            const bf16* __restrict__ vtws, const float* __restrict__ comb,
            const float* __restrict__ gM, bf16* __restrict__ yws) {
  const int lane = threadIdx.x & 63, wv = threadIdx.x >> 6;
  const int rr = lane & 15, g = lane >> 4;
  const int id = blockIdx.x;
  const int xcd = id & 7, t2 = id >> 3;
  const int qt = t2 & 7, gh = t2 >> 3;
  const int grp = gh * 8 + xcd;                 // bijective; 8 qt-blocks per grp on same XCD
  const int h = grp & 7, wid = grp >> 3;
  const int b = wid >> 3;
  const bool win7 = (wid & 7) == 7;
  const int iA = qt * 128 + wv * 16 + rr;       // q-rows (thread-local); iB = iA + 64
  const int iB = iA + 64;
  const bf16* qbase = qws + ((size_t)grp << 15);
  const bf16* kbase = kws + ((size_t)grp << 15);
  const bf16* vbase = vtws + ((size_t)grp << 15);
  const bf16x8 qfA = *(const bf16x8*)(qbase + (iA << 5) + g * 8);  // pre-scaled q
  const bf16x8 qfB = *(const bf16x8*)(qbase + (iB << 5) + g * 8);
  // (iA+64)&63 == iA&63  -> comb row shared; 512%128==0 -> mask side shared.
  const float* crow = comb + (b * 8 + h) * 4096 + (iA & 63) * 64;
  f32x4 b00 = *(const f32x4*)(crow + g * 8);        // keys kb(64-align) + 8g + r
  f32x4 b01 = *(const f32x4*)(crow + g * 8 + 4);    // keys kb + 8g + 4 + r
  f32x4 b10 = *(const f32x4*)(crow + 32 + g * 8);   // keys kb+32 + 8g + r
  f32x4 b11 = *(const f32x4*)(crow + 32 + g * 8 + 4);
  const bool ilow = iA < 512;
  const float M = gM[grp];
  const float cLo = ((win7 && !ilow) ? -100.0f : 0.0f) - M;
  const float cHi = ((win7 && ilow) ? -100.0f : 0.0f) - M;
#pragma unroll
  for (int r = 0; r < 4; ++r) { b00[r] += cLo; b01[r] += cLo; b10[r] += cLo; b11[r] += cLo; }

  const int kp = 8 * (rr >> 2) + (rr & 3);      // permuted K-row so P^T feeds PV B-frag
  const bf16* krow = kbase + (kp << 5) + g * 8; // row stride 32 elems
  const bf16* vrow0 = vbase + (rr << 10) + g * 8;
  const bf16* vrow1 = vbase + ((16 + rr) << 10) + g * 8;

  f32x4 o0A = {}, o1A = {}, o0B = {}, o1B = {};
  f32x4 laA = {}, laB = {};

  // prologue: chunk 0
  bf16x8 cKA = *(const bf16x8*)(krow);
  bf16x8 cKB = *(const bf16x8*)(krow + (4 << 5));
  bf16x8 cVA = *(const bf16x8*)(vrow0);
  bf16x8 cVB = *(const bf16x8*)(vrow1);

  // chunk C (keys C*32..C*32+31): QK -> reload K in place -> softmax -> PV -> reload V.
#define ATTN_STEP32S(C, B0, B1)                                                        \
  {                                                                                    \
    f32x4 zero = {};                                                                   \
    f32x4 sA0 = __builtin_amdgcn_mfma_f32_16x16x32_bf16(cKA, qfA, zero, 0, 0, 0);      \
    f32x4 sA1 = __builtin_amdgcn_mfma_f32_16x16x32_bf16(cKB, qfA, zero, 0, 0, 0);      \
    f32x4 sB0 = __builtin_amdgcn_mfma_f32_16x16x32_bf16(cKA, qfB, zero, 0, 0, 0);      \
    f32x4 sB1 = __builtin_amdgcn_mfma_f32_16x16x32_bf16(cKB, qfB, zero, 0, 0, 0);      \
    if ((C) < 31) {                                                                    \
      const int kn_ = ((C) + 1) * 32;                                                  \
      cKA = *(const bf16x8*)(krow + (kn_ << 5));                                       \
      cKB = *(const bf16x8*)(krow + ((kn_ + 4) << 5));                                 \
    }                                                                                  \
    f32x4 pA0, pA1, pB0, pB1;                                                          \
    _Pragma("unroll")                                                                  \
    for (int r = 0; r < 4; ++r) {                                                      \
      pA0[r] = __expf(sA0[r] + B0[r]); pA1[r] = __expf(sA1[r] + B1[r]);                \
      pB0[r] = __expf(sB0[r] + B0[r]); pB1[r] = __expf(sB1[r] + B1[r]);                \
    }                                                                                  \
    laA += pA0 + pA1; laB += pB0 + pB1;                                                \
    bf16x8 paA, paB;                                                                   \
    _Pragma("unroll")                                                                  \
    for (int r = 0; r < 4; ++r) {                                                      \
      paA[r] = (bf16)pA0[r]; paA[r + 4] = (bf16)pA1[r];                                \
      paB[r] = (bf16)pB0[r]; paB[r + 4] = (bf16)pB1[r];                                \
    }                                                                                  \
    o0A = __builtin_amdgcn_mfma_f32_16x16x32_bf16(cVA, paA, o0A, 0, 0, 0);             \
    o1A = __builtin_amdgcn_mfma_f32_16x16x32_bf16(cVB, paA, o1A, 0, 0, 0);             \
    o0B = __builtin_amdgcn_mfma_f32_16x16x32_bf16(cVA, paB, o0B, 0, 0, 0);             \
    o1B = __builtin_amdgcn_mfma_f32_16x16x32_bf16(cVB, paB, o1B, 0, 0, 0);             \
    if ((C) < 31) {                                                                    \
      const int kn_ = ((C) + 1) * 32;                                                  \
      cVA = *(const bf16x8*)(vrow0 + kn_);                                             \
      cVB = *(const bf16x8*)(vrow1 + kn_);                                             \
    }                                                                                  \
  }

#pragma unroll
  for (int t = 0; t < 8; ++t) {
    ATTN_STEP32S(2 * t, b00, b01);
    ATTN_STEP32S(2 * t + 1, b10, b11);
  }
  {
    const float dlt = cHi - cLo;
#pragma unroll
    for (int r = 0; r < 4; ++r) { b00[r] += dlt; b01[r] += dlt; b10[r] += dlt; b11[r] += dlt; }
  }
#pragma unroll
  for (int t = 8; t < 16; ++t) {
    ATTN_STEP32S(2 * t, b00, b01);
    ATTN_STEP32S(2 * t + 1, b10, b11);
  }
#undef ATTN_STEP32S

  // epilogue: per-fragment row-sum reduction (2 shuffles each) + store
  {
    float l = (laA[0] + laA[1]) + (laA[2] + laA[3]);
    l += __shfl_xor(l, 16);
    l += __shfl_xor(l, 32);
    const float inv = 1.0f / l;
    bf16* ybase = yws + (size_t)((wid << 10) + iA) * 256 + h * 32;
    union { u16 us[4]; uint2 u2; } pk;
#pragma unroll
    for (int r = 0; r < 4; ++r) { bf16 bv = (bf16)(o0A[r] * inv); pk.us[r] = *(const u16*)&bv; }
    *(uint2*)(ybase + g * 4) = pk.u2;
#pragma unroll
    for (int r = 0; r < 4; ++r) { bf16 bv = (bf16)(o1A[r] * inv); pk.us[r] = *(const u16*)&bv; }
    *(uint2*)(ybase + 16 + g * 4) = pk.u2;
  }
  {
    float l = (laB[0] + laB[1]) + (laB[2] + laB[3]);
    l += __shfl_xor(l, 16);
    l += __shfl_xor(l, 32);
    const float inv = 1.0f / l;
    bf16* ybase = yws + (size_t)((wid << 10) + iB) * 256 + h * 32;
    union { u16 us[4]; uint2 u2; } pk;
#pragma unroll
    for (int r = 0; r < 4; ++r) { bf16 bv = (bf16)(o0B[r] * inv); pk.us[r] = *(const u16*)&bv; }
    *(uint2*)(ybase + g * 4) = pk.u2;
#pragma unroll
    for (int r = 0; r < 4; ++r) { bf16 bv = (bf16)(o1B[r] * inv); pk.us[r] = *(const u16*)&bv; }
    *(uint2*)(ybase + 16 + g * 4) = pk.u2;
  }
}

// ---------------- kernel 4: proj GEMM, roll-back scatter ----------------
__global__ __launch_bounds__(256) void proj_k(const bf16* __restrict__ yws, const bf16* __restrict__ pwb,
                                              const float* __restrict__ pb, float* __restrict__ out) {
  __shared__ __align__(16) bf16 lA[128 * 64];
  __shared__ __align__(16) bf16 lB[128 * 64];
  const int lane = threadIdx.x & 63, wv = threadIdx.x >> 6;
  const int rr = lane & 15, g = lane >> 4;
  const int wr = wv >> 1, wc = wv & 1;
  const int bid = blockIdx.x;
  const int tt = (bid & 7) * 32 + (bid >> 3);
  const int mtile = tt >> 1, ntile = tt & 1;
  const int mb = mtile * 128, nb2 = ntile * 128;
  const int arow = lane >> 3;
  const int sg = ((lane & 7) ^ arow) << 3;
  const int axor = rr & 7;
  f32x4 acc[4][4] = {};
  for (int kb = 0; kb < 256; kb += 64) {
#pragma unroll
    for (int q = 0; q < 4; ++q) {
      const int rowp = (wv * 4 + q) * 8 + arow;
      glds16(yws + (size_t)(mb + rowp) * 256 + kb + sg, &lA[(wv * 4 + q) * 512]);
      glds16(pwb + (nb2 + rowp) * 256 + kb + sg, &lB[(wv * 4 + q) * 512]);
    }
    __syncthreads();
#pragma unroll
    for (int ks = 0; ks < 2; ++ks) {
      bf16x8 af[4], bfr[4];
#pragma unroll
      for (int rt = 0; rt < 4; ++rt)
        af[rt] = *(const bf16x8*)&lA[(wr * 64 + rt * 16 + rr) * 64 + (((ks << 2) | g) ^ axor) * 8];
#pragma unroll
      for (int ct = 0; ct < 4; ++ct)
        bfr[ct] = *(const bf16x8*)&lB[(wc * 64 + ct * 16 + rr) * 64 + (((ks << 2) | g) ^ axor) * 8];
#pragma unroll
      for (int rt = 0; rt < 4; ++rt)
#pragma unroll
        for (int ct = 0; ct < 4; ++ct)
          acc[rt][ct] = __builtin_amdgcn_mfma_f32_16x16x32_bf16(af[rt], bfr[ct], acc[rt][ct], 0, 0, 0);
    }
    __syncthreads();
  }
#pragma unroll
  for (int ct = 0; ct < 4; ++ct) {
    const int c2 = nb2 + wc * 64 + ct * 16 + rr;
    const float bc = pb[c2];
#pragma unroll
    for (int rt = 0; rt < 4; ++rt) {
#pragma unroll
      for (int r = 0; r < 4; ++r) {
        const int m = mb + wr * 64 + rt * 16 + g * 4 + r;
        const int wid = m >> 10, n = m & 1023;
        const int bb = wid >> 3;
        const int hh = ((wid & 7) * 64 + (n >> 4) + 32) & 511;  // roll(out, +32)
        out[(((bb * 512 + hh) * 16 + (n & 15)) << 8) + c2] = acc[rt][ct][r] + bc;
      }
    }
  }
}

extern "C" void kernel_launch(void* const* d_in, const int* in_sizes, int n_in,
                              void* d_out, int out_size, void* d_ws, size_t ws_size,
                              hipStream_t stream) {
  const float* x     = (const float*)d_in[0];
  const float* loc   = (const float*)d_in[1];
  const float* qkvw  = (const float*)d_in[2];
  const float* qkvb  = (const float*)d_in[3];
  const float* projw = (const float*)d_in[4];
  const float* projb = (const float*)d_in[5];
  const float* tt    = (const float*)d_in[6];
  const float* tx    = (const float*)d_in[7];
  const float* ty    = (const float*)d_in[8];
  const float* tz    = (const float*)d_in[9];
  char* ws = (char*)d_ws;
  bf16* qws   = (bf16*)(ws + OFF_Q);
  bf16* kws   = (bf16*)(ws + OFF_K);
  bf16* vtws  = (bf16*)(ws + OFF_VT);
  bf16* yws   = (bf16*)(ws + OFF_Y);
  bf16* xb    = (bf16*)(ws + OFF_Y);     // aliases yws; dead before attn writes
  float* comb = (float*)(ws + OFF_COMB);
  bf16* pwb   = (bf16*)(ws + OFF_PWB);
  bf16* wb    = (bf16*)(ws + OFF_WB);
  float* bmax = (float*)(ws + OFF_BMAX);
  float* gM   = (float*)(ws + OFF_GM);
  float* out = (float*)d_out;

  build_comb_k<<<16, 256, 0, stream>>>(loc, tt, tx, ty, tz, comb, bmax);
  cvt_x_k<<<2048, 256, 0, stream>>>(x, xb);
  cvt_w_k<<<128, 256, 0, stream>>>(qkvw, projw, wb, pwb);
  qkv_k<<<768, 256, 0, stream>>>(xb, wb, qkvb, qws, kws, vtws);
  norm_k<<<128, 256, 0, stream>>>(qws, kws, bmax, gM);
  attn_k<<<1024, 256, 0, stream>>>(qws, kws, vtws, comb, gM, yws);
  proj_k<<<256, 256, 0, stream>>>(yws, pwb, projb, out);
}

// Round 13
// 95.837 us; speedup vs baseline: 3.1213x; 3.1162x over previous
//
#include <hip/hip_runtime.h>
#include <hip/hip_bf16.h>

typedef __bf16 bf16;
typedef __bf16 bf16x8 __attribute__((ext_vector_type(8)));
typedef float f32x4 __attribute__((ext_vector_type(4)));
typedef unsigned short u16;

// workspace offsets (bytes)
static constexpr size_t OFF_Q    = 0;          // [16][8][1024][32] bf16  (q pre-scaled by 32^-0.5 * log2e)
static constexpr size_t OFF_K    = 8388608;    // [16][8][1024][32] bf16
static constexpr size_t OFF_VT   = 16777216;   // [16][8][32][1024] bf16 (V transposed)
static constexpr size_t OFF_Y    = 25165824;   // [16][1024][256]  bf16 (attn out) -- xb aliases this
static constexpr size_t OFF_COMB = 33554432;   // [2][8][64][64]   f32 (natural units)
static constexpr size_t OFF_PWB  = 33816576;   // [256][256]  bf16 proj weight
static constexpr size_t OFF_WB   = 33947648;   // [768][256]  bf16 qkv weight
static constexpr size_t OFF_BMAX = 34340864;   // [16] f32 per-(b,h) bias max (natural units)
static constexpr size_t OFF_GM   = 34340928;   // [128] f32 per-(wid,h) softmax shift M (log2 units)

static constexpr float LOG2E = 1.4426950408889634f;

__device__ __forceinline__ int clampi(int v, int lo, int hi) {
  return v < lo ? lo : (v > hi ? hi : v);
}

__device__ __forceinline__ void glds16(const bf16* src, bf16* dst) {
  __builtin_amdgcn_global_load_lds((const __attribute__((address_space(1))) void*)src,
                                   (__attribute__((address_space(3))) void*)dst,
                                   16, 0, 0);
}

__device__ __forceinline__ bf16x8 cvt8(const float* p) {
  f32x4 a = *(const f32x4*)p;
  f32x4 b = *(const f32x4*)(p + 4);
  bf16x8 r;
  r[0] = (bf16)a[0]; r[1] = (bf16)a[1]; r[2] = (bf16)a[2]; r[3] = (bf16)a[3];
  r[4] = (bf16)b[0]; r[5] = (bf16)b[1]; r[6] = (bf16)b[2]; r[7] = (bf16)b[3];
  return r;
}

// ---------------- kernel 1: combined bias table + per-(b,h) bias max ----------------
__global__ void build_comb_k(const float* __restrict__ loc, const float* __restrict__ tt,
                             const float* __restrict__ tx, const float* __restrict__ ty,
                             const float* __restrict__ tz, float* __restrict__ comb,
                             float* __restrict__ bmax) {
  const int b = blockIdx.x >> 3, h = blockIdx.x & 7;
  __shared__ float st[256];
  __shared__ float red[256];
  const int t = threadIdx.x;
  {
    const int i = t >> 4, j = t & 15;
    const float* li = loc + (b * 16 + i) * 3;
    const float* lj = loc + (b * 16 + j) * 3;
    const float G = (float)(111.32 / 100.0);
    float dx = li[0] - lj[0];
    float dy = li[1] - lj[1];
    float dz = li[2] - lj[2];
    int ix = clampi((int)rintf(dx / G + 25.0f), 0, 50);
    int iy = clampi((int)rintf(dy / G + 25.0f), 0, 50);
    int iz = clampi((int)rintf(dz / G + 5.0f), 0, 10);
    st[t] = tx[ix * 8 + h] + ty[iy * 8 + h] + tz[iz * 8 + h];
  }
  __syncthreads();
  float* out = comb + blockIdx.x * 4096;
  float lm = -1e30f;
  for (int e = t; e < 4096; e += 256) {
    int a = e >> 6, c = e & 63;
    float v = tt[(a - c + 63) * 8 + h] + st[((a & 15) << 4) | (c & 15)];
    out[e] = v;
    lm = fmaxf(lm, v);
  }
  red[t] = lm;
  __syncthreads();
  for (int s = 128; s > 0; s >>= 1) {
    if (t < s) red[t] = fmaxf(red[t], red[t + s]);
    __syncthreads();
  }
  if (t == 0) bmax[blockIdx.x] = red[0];
}

// ---------------- kernel 1b: fp32->bf16 conversions (x with roll gather; both weights) ----
__global__ __launch_bounds__(256) void cvt_all_k(const float* __restrict__ x, const float* __restrict__ w,
                                                 const float* __restrict__ pw, bf16* __restrict__ xb,
                                                 bf16* __restrict__ wb, bf16* __restrict__ pwb) {
  const int bid = blockIdx.x;
  if (bid < 2048) {
    const int tid = bid * 256 + threadIdx.x;
    const int e = tid * 8;
    const int m = e >> 8, k = e & 255;
    const int wid = m >> 10, n = m & 1023;
    const int bb = wid >> 3, wi = wid & 7, tw = n >> 4, ww = n & 15;
    const int hh = (wi * 64 + tw + 32) & 511;        // roll(x, -32)
    const float* src = x + (((bb * 512 + hh) * 16 + ww) << 8) + k;
    *(bf16x8*)(xb + e) = cvt8(src);
  } else {
    const int tid = (bid - 2048) * 256 + threadIdx.x;
    const int e = tid * 8;
    if (e < 768 * 256) {
      *(bf16x8*)(wb + e) = cvt8(w + e);
    } else {
      const int e2 = e - 768 * 256;
      *(bf16x8*)(pwb + e2) = cvt8(pw + e2);
    }
  }
}

// ---------------- kernel 2: QKV GEMM, LDS-staged, swizzled; q pre-scaled (incl log2e) ----
__global__ __launch_bounds__(256) void qkv_k(const bf16* __restrict__ xb, const bf16* __restrict__ wb,
                                             const float* __restrict__ qb, bf16* __restrict__ qws,
                                             bf16* __restrict__ kws, bf16* __restrict__ vtws) {
  __shared__ __align__(16) bf16 lA[128 * 64];
  __shared__ __align__(16) bf16 lB[128 * 64];
  const int lane = threadIdx.x & 63, wv = threadIdx.x >> 6;
  const int rr = lane & 15, g = lane >> 4;
  const int wr = wv >> 1, wc = wv & 1;
  const int bid = blockIdx.x;
  const int tt = (bid & 7) * 96 + (bid >> 3);
  const int mtile = tt / 6, ntile = tt % 6;
  const int mb = mtile * 128, nb2 = ntile * 128;
  const int arow = lane >> 3;
  const int sg = ((lane & 7) ^ arow) << 3;
  const int axor = rr & 7;
  f32x4 acc[4][4] = {};
  for (int kb = 0; kb < 256; kb += 64) {
#pragma unroll
    for (int q = 0; q < 4; ++q) {
      const int rowp = (wv * 4 + q) * 8 + arow;
      glds16(xb + (mb + rowp) * 256 + kb + sg, &lA[(wv * 4 + q) * 512]);
      glds16(wb + (nb2 + rowp) * 256 + kb + sg, &lB[(wv * 4 + q) * 512]);
    }
    __syncthreads();
#pragma unroll
    for (int ks = 0; ks < 2; ++ks) {
      bf16x8 af[4], bfr[4];
#pragma unroll
      for (int rt = 0; rt < 4; ++rt)
        af[rt] = *(const bf16x8*)&lA[(wr * 64 + rt * 16 + rr) * 64 + (((ks << 2) | g) ^ axor) * 8];
#pragma unroll
      for (int ct = 0; ct < 4; ++ct)
        bfr[ct] = *(const bf16x8*)&lB[(wc * 64 + ct * 16 + rr) * 64 + (((ks << 2) | g) ^ axor) * 8];
#pragma unroll
      for (int rt = 0; rt < 4; ++rt)
#pragma unroll
        for (int ct = 0; ct < 4; ++ct)
          acc[rt][ct] = __builtin_amdgcn_mfma_f32_16x16x32_bf16(af[rt], bfr[ct], acc[rt][ct], 0, 0, 0);
    }
    __syncthreads();
  }
  const int qkvi = (nb2 >> 8);
  // fold 32^-0.5 * log2(e) into q so attn uses exp2 directly
  const float mult = (qkvi == 0) ? 0.17677669529663687f * 1.4426950408889634f : 1.0f;
#pragma unroll
  for (int ct = 0; ct < 4; ++ct) {
    const int c2 = nb2 + wc * 64 + ct * 16 + rr;
    const float bc = qb[c2];
    const int h2 = (c2 & 255) >> 5, d = c2 & 31;
#pragma unroll
    for (int rt = 0; rt < 4; ++rt) {
      const int m0 = mb + wr * 64 + rt * 16 + g * 4;
      const int wid = m0 >> 10, n0 = m0 & 1023;
      if (qkvi == 2) {
        union { u16 us[4]; uint2 u2; } pk;
#pragma unroll
        for (int r = 0; r < 4; ++r) {
          bf16 bv = (bf16)(acc[rt][ct][r] + bc);
          pk.us[r] = *(const u16*)&bv;
        }
        *(uint2*)(vtws + ((size_t)((wid * 8 + h2) * 32 + d) << 10) + n0) = pk.u2;
      } else {
        bf16* bp = (qkvi ? kws : qws) + ((size_t)(wid * 8 + h2) << 15) + d;
#pragma unroll
        for (int r = 0; r < 4; ++r) bp[(size_t)(n0 + r) << 5] = (bf16)((acc[rt][ct][r] + bc) * mult);
      }
    }
  }
}

// ---------------- kernel 2b: per-group shift M = ||q'||max*||k||max + bmax (log2 units) ----
__global__ __launch_bounds__(256) void norm_k(const bf16* __restrict__ qws, const bf16* __restrict__ kws,
                                              const float* __restrict__ bmax, float* __restrict__ gM) {
  const int grp = blockIdx.x;                 // wid*8 + h
  const int t = threadIdx.x;
  const bf16* qb = qws + ((size_t)grp << 15);
  const bf16* kb = kws + ((size_t)grp << 15);
  float qm = 0.0f, km = 0.0f;
#pragma unroll
  for (int rw = 0; rw < 4; ++rw) {
    const int r = rw * 256 + t;
    float sq = 0.0f, sk = 0.0f;
#pragma unroll
    for (int d8 = 0; d8 < 4; ++d8) {
      bf16x8 vq = *(const bf16x8*)(qb + r * 32 + d8 * 8);
      bf16x8 vk = *(const bf16x8*)(kb + r * 32 + d8 * 8);
#pragma unroll
      for (int e = 0; e < 8; ++e) {
        float a = (float)vq[e]; sq += a * a;
        float c = (float)vk[e]; sk += c * c;
      }
    }
    qm = fmaxf(qm, sq); km = fmaxf(km, sk);
  }
  __shared__ float rq[256], rk[256];
  rq[t] = qm; rk[t] = km;
  __syncthreads();
  for (int s = 128; s > 0; s >>= 1) {
    if (t < s) { rq[t] = fmaxf(rq[t], rq[t + s]); rk[t] = fmaxf(rk[t], rk[t + s]); }
    __syncthreads();
  }
  if (t == 0) {
    const int b = grp >> 6, h = grp & 7;
    // q already carries log2e; bias max converted here. +0.01 margin (log2 units).
    gM[grp] = sqrtf(rq[0] * rk[0]) * 1.0005f + bmax[b * 8 + h] * LOG2E + 0.01f;
  }
}

// ---------------- kernel 3: attention (r10 structure, exp2 domain) ----------------
// Dual-q waves, 32-key chunks, loads at use-site (the one schedule the allocator
// doesn't spill: VGPR 56). p = exp2(s + b) with log2e pre-folded into q/bias/mask/M.
__global__ __launch_bounds__(256, 4)
void attn_k(const bf16* __restrict__ qws, const bf16* __restrict__ kws,
            const bf16* __restrict__ vtws, const float* __restrict__ comb,
            const float* __restrict__ gM, bf16* __restrict__ yws) {
  const int lane = threadIdx.x & 63, wv = threadIdx.x >> 6;
  const int rr = lane & 15, g = lane >> 4;
  const int id = blockIdx.x;
  const int xcd = id & 7, t2 = id >> 3;
  const int qt = t2 & 7, gh = t2 >> 3;
  const int grp = gh * 8 + xcd;                 // bijective; 8 qt-blocks per grp on same XCD
  const int h = grp & 7, wid = grp >> 3;
  const int b = wid >> 3;
  const bool win7 = (wid & 7) == 7;
  const int iA = qt * 128 + wv * 16 + rr;       // q-rows (thread-local); iB = iA + 64
  const int iB = iA + 64;
  const bf16* qbase = qws + ((size_t)grp << 15);
  const bf16* kbase = kws + ((size_t)grp << 15);
  const bf16* vbase = vtws + ((size_t)grp << 15);
  const bf16x8 qfA = *(const bf16x8*)(qbase + (iA << 5) + g * 8);  // pre-scaled q (log2 domain)
  const bf16x8 qfB = *(const bf16x8*)(qbase + (iB << 5) + g * 8);
  const float* crow = comb + (b * 8 + h) * 4096 + (iA & 63) * 64;
  f32x4 b00 = *(const f32x4*)(crow + g * 8);        // keys kb(64-align) + 8g + r
  f32x4 b01 = *(const f32x4*)(crow + g * 8 + 4);    // keys kb + 8g + 4 + r
  f32x4 b10 = *(const f32x4*)(crow + 32 + g * 8);   // keys kb+32 + 8g + r
  f32x4 b11 = *(const f32x4*)(crow + 32 + g * 8 + 4);
  const bool ilow = iA < 512;
  const float M = gM[grp];
  const float MASKL = -100.0f * LOG2E;
  const float cLo = ((win7 && !ilow) ? MASKL : 0.0f) - M;
  const float cHi = ((win7 && ilow) ? MASKL : 0.0f) - M;
#pragma unroll
  for (int r = 0; r < 4; ++r) {
    b00[r] = b00[r] * LOG2E + cLo; b01[r] = b01[r] * LOG2E + cLo;
    b10[r] = b10[r] * LOG2E + cLo; b11[r] = b11[r] * LOG2E + cLo;
  }

  const int kp = 8 * (rr >> 2) + (rr & 3);      // permuted K-row so P^T feeds PV B-frag
  const bf16* krow = kbase + (kp << 5) + g * 8; // row stride 32 elems
  const bf16* vrow0 = vbase + (rr << 10) + g * 8;
  const bf16* vrow1 = vbase + ((16 + rr) << 10) + g * 8;

  f32x4 o0A = {}, o1A = {}, o0B = {}, o1B = {};
  f32x4 laA = {}, laB = {};

  // one 32-key chunk: keys KB..KB+31 (KB multiple of 32), bias regs B0,B1 per 64-phase
#define ATTN_STEP32(KB, B0, B1)                                                        \
  {                                                                                    \
    const int kb_ = (KB);                                                              \
    bf16x8 kA = *(const bf16x8*)(krow + (kb_ << 5));                                   \
    bf16x8 kB = *(const bf16x8*)(krow + ((kb_ + 4) << 5));                             \
    bf16x8 vA = *(const bf16x8*)(vrow0 + kb_);                                         \
    bf16x8 vB = *(const bf16x8*)(vrow1 + kb_);                                         \
    f32x4 zero = {};                                                                   \
    f32x4 sA0 = __builtin_amdgcn_mfma_f32_16x16x32_bf16(kA, qfA, zero, 0, 0, 0);       \
    f32x4 sA1 = __builtin_amdgcn_mfma_f32_16x16x32_bf16(kB, qfA, zero, 0, 0, 0);       \
    f32x4 sB0 = __builtin_amdgcn_mfma_f32_16x16x32_bf16(kA, qfB, zero, 0, 0, 0);       \
    f32x4 sB1 = __builtin_amdgcn_mfma_f32_16x16x32_bf16(kB, qfB, zero, 0, 0, 0);       \
    f32x4 pA0, pA1, pB0, pB1;                                                          \
    _Pragma("unroll")                                                                  \
    for (int r = 0; r < 4; ++r) {                                                      \
      pA0[r] = __builtin_amdgcn_exp2f(sA0[r] + B0[r]);                                 \
      pA1[r] = __builtin_amdgcn_exp2f(sA1[r] + B1[r]);                                 \
      pB0[r] = __builtin_amdgcn_exp2f(sB0[r] + B0[r]);                                 \
      pB1[r] = __builtin_amdgcn_exp2f(sB1[r] + B1[r]);                                 \
    }                                                                                  \
    laA += pA0 + pA1; laB += pB0 + pB1;                                                \
    bf16x8 paA, paB;                                                                   \
    _Pragma("unroll")                                                                  \
    for (int r = 0; r < 4; ++r) {                                                      \
      paA[r] = (bf16)pA0[r]; paA[r + 4] = (bf16)pA1[r];                                \
      paB[r] = (bf16)pB0[r]; paB[r + 4] = (bf16)pB1[r];                                \
    }                                                                                  \
    o0A = __builtin_amdgcn_mfma_f32_16x16x32_bf16(vA, paA, o0A, 0, 0, 0);              \
    o1A = __builtin_amdgcn_mfma_f32_16x16x32_bf16(vB, paA, o1A, 0, 0, 0);              \
    o0B = __builtin_amdgcn_mfma_f32_16x16x32_bf16(vA, paB, o0B, 0, 0, 0);              \
    o1B = __builtin_amdgcn_mfma_f32_16x16x32_bf16(vB, paB, o1B, 0, 0, 0);              \
  }

#pragma unroll
  for (int t = 0; t < 8; ++t) {
    ATTN_STEP32(t * 64, b00, b01);
    ATTN_STEP32(t * 64 + 32, b10, b11);
  }
  {
    const float dlt = cHi - cLo;
#pragma unroll
    for (int r = 0; r < 4; ++r) { b00[r] += dlt; b01[r] += dlt; b10[r] += dlt; b11[r] += dlt; }
  }
#pragma unroll
  for (int t = 8; t < 16; ++t) {
    ATTN_STEP32(t * 64, b00, b01);
    ATTN_STEP32(t * 64 + 32, b10, b11);
  }
#undef ATTN_STEP32

  // epilogue: per-fragment row-sum reduction (2 shuffles each) + store
  {
    float l = (laA[0] + laA[1]) + (laA[2] + laA[3]);
    l += __shfl_xor(l, 16);
    l += __shfl_xor(l, 32);
    const float inv = 1.0f / l;
    bf16* ybase = yws + (size_t)((wid << 10) + iA) * 256 + h * 32;
    union { u16 us[4]; uint2 u2; } pk;
#pragma unroll
    for (int r = 0; r < 4; ++r) { bf16 bv = (bf16)(o0A[r] * inv); pk.us[r] = *(const u16*)&bv; }
    *(uint2*)(ybase + g * 4) = pk.u2;
#pragma unroll
    for (int r = 0; r < 4; ++r) { bf16 bv = (bf16)(o1A[r] * inv); pk.us[r] = *(const u16*)&bv; }
    *(uint2*)(ybase + 16 + g * 4) = pk.u2;
  }
  {
    float l = (laB[0] + laB[1]) + (laB[2] + laB[3]);
    l += __shfl_xor(l, 16);
    l += __shfl_xor(l, 32);
    const float inv = 1.0f / l;
    bf16* ybase = yws + (size_t)((wid << 10) + iB) * 256 + h * 32;
    union { u16 us[4]; uint2 u2; } pk;
#pragma unroll
    for (int r = 0; r < 4; ++r) { bf16 bv = (bf16)(o0B[r] * inv); pk.us[r] = *(const u16*)&bv; }
    *(uint2*)(ybase + g * 4) = pk.u2;
#pragma unroll
    for (int r = 0; r < 4; ++r) { bf16 bv = (bf16)(o1B[r] * inv); pk.us[r] = *(const u16*)&bv; }
    *(uint2*)(ybase + 16 + g * 4) = pk.u2;
  }
}

// ---------------- kernel 4: proj GEMM, roll-back scatter ----------------
__global__ __launch_bounds__(256) void proj_k(const bf16* __restrict__ yws, const bf16* __restrict__ pwb,
                                              const float* __restrict__ pb, float* __restrict__ out) {
  __shared__ __align__(16) bf16 lA[128 * 64];
  __shared__ __align__(16) bf16 lB[128 * 64];
  const int lane = threadIdx.x & 63, wv = threadIdx.x >> 6;
  const int rr = lane & 15, g = lane >> 4;
  const int wr = wv >> 1, wc = wv & 1;
  const int bid = blockIdx.x;
  const int tt = (bid & 7) * 32 + (bid >> 3);
  const int mtile = tt >> 1, ntile = tt & 1;
  const int mb = mtile * 128, nb2 = ntile * 128;
  const int arow = lane >> 3;
  const int sg = ((lane & 7) ^ arow) << 3;
  const int axor = rr & 7;
  f32x4 acc[4][4] = {};
  for (int kb = 0; kb < 256; kb += 64) {
#pragma unroll
    for (int q = 0; q < 4; ++q) {
      const int rowp = (wv * 4 + q) * 8 + arow;
      glds16(yws + (size_t)(mb + rowp) * 256 + kb + sg, &lA[(wv * 4 + q) * 512]);
      glds16(pwb + (nb2 + rowp) * 256 + kb + sg, &lB[(wv * 4 + q) * 512]);
    }
    __syncthreads();
#pragma unroll
    for (int ks = 0; ks < 2; ++ks) {
      bf16x8 af[4], bfr[4];
#pragma unroll
      for (int rt = 0; rt < 4; ++rt)
        af[rt] = *(const bf16x8*)&lA[(wr * 64 + rt * 16 + rr) * 64 + (((ks << 2) | g) ^ axor) * 8];
#pragma unroll
      for (int ct = 0; ct < 4; ++ct)
        bfr[ct] = *(const bf16x8*)&lB[(wc * 64 + ct * 16 + rr) * 64 + (((ks << 2) | g) ^ axor) * 8];
#pragma unroll
      for (int rt = 0; rt < 4; ++rt)
#pragma unroll
        for (int ct = 0; ct < 4; ++ct)
          acc[rt][ct] = __builtin_amdgcn_mfma_f32_16x16x32_bf16(af[rt], bfr[ct], acc[rt][ct], 0, 0, 0);
    }
    __syncthreads();
  }
#pragma unroll
  for (int ct = 0; ct < 4; ++ct) {
    const int c2 = nb2 + wc * 64 + ct * 16 + rr;
    const float bc = pb[c2];
#pragma unroll
    for (int rt = 0; rt < 4; ++rt) {
#pragma unroll
      for (int r = 0; r < 4; ++r) {
        const int m = mb + wr * 64 + rt * 16 + g * 4 + r;
        const int wid = m >> 10, n = m & 1023;
        const int bb = wid >> 3;
        const int hh = ((wid & 7) * 64 + (n >> 4) + 32) & 511;  // roll(out, +32)
        out[(((bb * 512 + hh) * 16 + (n & 15)) << 8) + c2] = acc[rt][ct][r] + bc;
      }
    }
  }
}

extern "C" void kernel_launch(void* const* d_in, const int* in_sizes, int n_in,
                              void* d_out, int out_size, void* d_ws, size_t ws_size,
                              hipStream_t stream) {
  const float* x     = (const float*)d_in[0];
  const float* loc   = (const float*)d_in[1];
  const float* qkvw  = (const float*)d_in[2];
  const float* qkvb  = (const float*)d_in[3];
  const float* projw = (const float*)d_in[4];
  const float* projb = (const float*)d_in[5];
  const float* tt    = (const float*)d_in[6];
  const float* tx    = (const float*)d_in[7];
  const float* ty    = (const float*)d_in[8];
  const float* tz    = (const float*)d_in[9];
  char* ws = (char*)d_ws;
  bf16* qws   = (bf16*)(ws + OFF_Q);
  bf16* kws   = (bf16*)(ws + OFF_K);
  bf16* vtws  = (bf16*)(ws + OFF_VT);
  bf16* yws   = (bf16*)(ws + OFF_Y);
  bf16* xb    = (bf16*)(ws + OFF_Y);     // aliases yws; dead before attn writes
  float* comb = (float*)(ws + OFF_COMB);
  bf16* pwb   = (bf16*)(ws + OFF_PWB);
  bf16* wb    = (bf16*)(ws + OFF_WB);
  float* bmax = (float*)(ws + OFF_BMAX);
  float* gM   = (float*)(ws + OFF_GM);
  float* out = (float*)d_out;

  build_comb_k<<<16, 256, 0, stream>>>(loc, tt, tx, ty, tz, comb, bmax);
  cvt_all_k<<<2176, 256, 0, stream>>>(x, qkvw, projw, xb, wb, pwb);
  qkv_k<<<768, 256, 0, stream>>>(xb, wb, qkvb, qws, kws, vtws);
  norm_k<<<128, 256, 0, stream>>>(qws, kws, bmax, gM);
  attn_k<<<1024, 256, 0, stream>>>(qws, kws, vtws, comb, gM, yws);
  proj_k<<<256, 256, 0, stream>>>(yws, pwb, projb, out);
}